// Round 10
// baseline (350.834 us; speedup 1.0000x reference)
//
#include <hip/hip_runtime.h>
#include <hip/hip_bf16.h>

#define NPTS 8192
#define DIM  512
#define NHEAD 8
#define HDIM 64

typedef short bf16x8 __attribute__((ext_vector_type(8)));   // 8 bf16 = 4 VGPRs
typedef float f32x4  __attribute__((ext_vector_type(4)));   // MFMA C/D

#define GLOBAL_AS __attribute__((address_space(1)))
#define LDS_AS    __attribute__((address_space(3)))

#if __has_builtin(__builtin_amdgcn_exp2f)
#define EXP2F(x) __builtin_amdgcn_exp2f(x)
#else
#define EXP2F(x) __expf((x) * 0.6931471805599453f)
#endif

// fp32 -> bf16 round-nearest-even (scalar)
__device__ __forceinline__ unsigned short f2bf(float f) {
    union { float f; unsigned int u; } v; v.f = f;
    unsigned int r = v.u + 0x7FFFu + ((v.u >> 16) & 1u);
    return (unsigned short)(r >> 16);
}
__device__ __forceinline__ float bf2f_lo(unsigned int u) {
    union { unsigned int i; float f; } v; v.i = u << 16;
    return v.f;
}
__device__ __forceinline__ float bf2f_hi(unsigned int u) {
    union { unsigned int i; float f; } v; v.i = u & 0xFFFF0000u;
    return v.f;
}
// packed 2x f32 -> bf16 pair (v_cvt_pk_bf16_f32 on gfx950)
__device__ __forceinline__ unsigned int pk2bf(float a, float b) {
    __hip_bfloat162 h = __float22bfloat162_rn(float2{a, b});
    union { __hip_bfloat162 h; unsigned int u; } v; v.h = h;
    return v.u;
}

// ---------------------------------------------------------------------------
// Fused prep: [0,2048) cvt_x | [2048,2240) tr_w | [2240,2304) tr_wo
// ---------------------------------------------------------------------------
__global__ __launch_bounds__(256) void prep_kernel(
    const float* __restrict__ x,
    const float* __restrict__ Wq, const float* __restrict__ Wk,
    const float* __restrict__ Wv, const float* __restrict__ Wo,
    unsigned short* __restrict__ xbf, unsigned short* __restrict__ wtq,
    unsigned short* __restrict__ wot)
{
    __shared__ float tile[64][65];
    const int bid = blockIdx.x;
    const int t = threadIdx.x;

    if (bid < 2048) {               // x fp32 -> bf16, 8 elems/thread
        int gid = bid * 256 + t;
        float4 a = ((const float4*)x)[gid * 2];
        float4 b = ((const float4*)x)[gid * 2 + 1];
        uint4 u;
        u.x = pk2bf(a.x, a.y); u.y = pk2bf(a.z, a.w);
        u.z = pk2bf(b.x, b.y); u.w = pk2bf(b.z, b.w);
        ((uint4*)xbf)[gid] = u;
    } else if (bid < 2240) {        // Wq/Wk/Wv -> wtq [zh][64][512] transposed
        int wid = bid - 2048;
        int zh = wid >> 3, z = zh >> 3, h = zh & 7;
        const float* src = (z == 0 ? Wq : z == 1 ? Wk : Wv) + (size_t)h * DIM * HDIM;
        unsigned short* dst = wtq + (size_t)zh * HDIM * DIM;
        int k0 = (wid & 7) * 64;
        int c = t & 63, r = t >> 6;
        #pragma unroll
        for (int i = 0; i < 16; ++i)
            tile[r + 4 * i][c] = src[(size_t)(k0 + r + 4 * i) * HDIM + c];
        __syncthreads();
        #pragma unroll
        for (int i = 0; i < 16; ++i)
            dst[(size_t)(r + 4 * i) * DIM + k0 + c] = f2bf(tile[c][r + 4 * i]);
    } else {                        // Wo -> wot [e_out][k] transposed
        int oid = bid - 2240;
        int k0 = (oid & 7) * 64, e0 = (oid >> 3) * 64;
        int c = t & 63, r = t >> 6;
        #pragma unroll
        for (int i = 0; i < 16; ++i)
            tile[r + 4 * i][c] = Wo[(size_t)(k0 + r + 4 * i) * DIM + e0 + c];
        __syncthreads();
        #pragma unroll
        for (int i = 0; i < 16; ++i)
            wot[(size_t)(e0 + r + 4 * i) * DIM + k0 + c] = f2bf(tile[c][r + 4 * i]);
    }
}

// ---------------------------------------------------------------------------
// QKV projection, bf16 MFMA, direct-global frags.
//   z=0: q_bf[h][n][e]  (scale*log2e folded)   z=1: k_bf[h][n][e]
//   z=2: vtp[h][e][pi(n)] = V^T, sigma-permuted per 32-key block
// ---------------------------------------------------------------------------
__global__ __launch_bounds__(256) void qkv_mfma_kernel(
    const unsigned short* __restrict__ xbf,   // [N][512] bf16
    const unsigned short* __restrict__ wtq,   // [24][64][512] bf16
    const float* __restrict__ bq, const float* __restrict__ bk,
    const float* __restrict__ bv,
    unsigned short* __restrict__ q_bf, unsigned short* __restrict__ k_bf,
    unsigned short* __restrict__ vt_bf)
{
    const int zh = blockIdx.y, z = zh >> 3, h = zh & 7;
    const unsigned short* W = wtq + (size_t)zh * HDIM * DIM;
    const float* b = (z == 0 ? bq : z == 1 ? bk : bv) + h * HDIM;
    const int t = threadIdx.x, w = t >> 6, lane = t & 63;
    const int l15 = lane & 15, quad = lane >> 4;
    const int r0 = blockIdx.x * 128 + w * 32;

    f32x4 O[2][4];
    #pragma unroll
    for (int mt = 0; mt < 2; ++mt)
        #pragma unroll
        for (int tn = 0; tn < 4; ++tn) O[mt][tn] = (f32x4){0.f, 0.f, 0.f, 0.f};

    for (int k0 = 0; k0 < DIM; k0 += 64) {
        bf16x8 af[2][2], bf[4][2];
        #pragma unroll
        for (int mt = 0; mt < 2; ++mt)
            #pragma unroll
            for (int kc = 0; kc < 2; ++kc)
                af[mt][kc] = *(const bf16x8*)
                    &xbf[(size_t)(r0 + 16 * mt + l15) * DIM + k0 + quad * 8 + 32 * kc];
        #pragma unroll
        for (int tn = 0; tn < 4; ++tn)
            #pragma unroll
            for (int kc = 0; kc < 2; ++kc)
                bf[tn][kc] = *(const bf16x8*)
                    &W[(size_t)(l15 + 16 * tn) * DIM + k0 + quad * 8 + 32 * kc];
        #pragma unroll
        for (int mt = 0; mt < 2; ++mt)
            #pragma unroll
            for (int tn = 0; tn < 4; ++tn) {
                O[mt][tn] = __builtin_amdgcn_mfma_f32_16x16x32_bf16(
                    af[mt][0], bf[tn][0], O[mt][tn], 0, 0, 0);
                O[mt][tn] = __builtin_amdgcn_mfma_f32_16x16x32_bf16(
                    af[mt][1], bf[tn][1], O[mt][tn], 0, 0, 0);
            }
    }

    if (z < 2) {
        unsigned short* outp = (z == 0 ? q_bf : k_bf) + (size_t)h * NPTS * HDIM;
        const float sc = (z == 0) ? 0.18033688011112042f : 1.0f;  // 0.125*log2e | 1
        #pragma unroll
        for (int mt = 0; mt < 2; ++mt)
            #pragma unroll
            for (int tn = 0; tn < 4; ++tn) {
                int e = l15 + 16 * tn;
                float be = b[e];
                #pragma unroll
                for (int r = 0; r < 4; ++r) {
                    int n = r0 + 16 * mt + quad * 4 + r;
                    outp[(size_t)n * HDIM + e] = f2bf((O[mt][tn][r] + be) * sc);
                }
            }
    } else {
        unsigned short* vt = vt_bf + (size_t)h * HDIM * NPTS;
        #pragma unroll
        for (int mt = 0; mt < 2; ++mt)
            #pragma unroll
            for (int tn = 0; tn < 4; ++tn) {
                int e = l15 + 16 * tn;
                float be = b[e];
                uint2 pk;
                pk.x = pk2bf(O[mt][tn][0] + be, O[mt][tn][1] + be);
                pk.y = pk2bf(O[mt][tn][2] + be, O[mt][tn][3] + be);
                *(uint2*)&vt[(size_t)e * NPTS + r0 + quad * 8 + mt * 4] = pk;
            }
    }
}

// ---------------------------------------------------------------------------
// MFMA flash attention, R10 = R9 + (a) lsum via ones-MFMA (deletes 28 VALU
// adds/iter + epilogue shuffles; MFMA hardware sums P^T over the tile's 32
// keys, result replicated over C rows), (b) loop-invariant zero-C operand
// (deletes per-iter zero-init movs). K+V staged in LDS, double-buffered,
// register-resident P, max-free softmax, k-split 2.
// ---------------------------------------------------------------------------
__global__ __launch_bounds__(256) void attn_kernel(
    const unsigned short* __restrict__ qg,   // [H][N][64] bf16, pre-scaled
    const unsigned short* __restrict__ kg,   // [H][N][64] bf16
    const unsigned short* __restrict__ vtg,  // [H][64][N] bf16, sigma-permuted
    unsigned short* __restrict__ opart,      // [2][N][DIM] bf16 unnormalized
    float* __restrict__ lpart)               // [2][H][N] fp32
{
    const int h  = blockIdx.y;
    const int ks = blockIdx.z;
    const int q0 = blockIdx.x * 128;
    const int kbase = ks * (NPTS / 2);
    const unsigned short* Q  = qg  + (size_t)h * NPTS * HDIM;
    const unsigned short* K  = kg  + (size_t)h * NPTS * HDIM;
    const unsigned short* Vt = vtg + (size_t)h * HDIM * NPTS;
    unsigned short* op = opart + (size_t)ks * NPTS * DIM;
    float* lp = lpart + (size_t)(ks * NHEAD + h) * NPTS;

    __shared__ __align__(16) unsigned short Klds[2][64 * 64];  // 16 KB
    __shared__ __align__(16) unsigned short Vlds[2][64 * 64];  // 16 KB

    const int t    = threadIdx.x;
    const int w    = t >> 6;
    const int lane = t & 63;
    const int l15  = lane & 15;
    const int quad = lane >> 4;

    const int koff0 = l15 * 64 + (quad ^ (l15 & 7)) * 8;
    const int koff1 = koff0 ^ 32;

    const int srow   = lane >> 3;
    const int schunk = (lane & 7) ^ srow;

    // Q B-frags
    bf16x8 qf[2][2];
    #pragma unroll
    for (int m = 0; m < 2; ++m)
        #pragma unroll
        for (int kc = 0; kc < 2; ++kc)
            qf[m][kc] = *(const bf16x8*)
                &Q[(size_t)(q0 + 32 * w + 16 * m + l15) * HDIM + quad * 8 + 32 * kc];

    // O^T accumulators [te][m]; lacc = ones-MFMA row-sum accumulator
    f32x4 OT[4][2], lacc[2];
    #pragma unroll
    for (int te = 0; te < 4; ++te)
        #pragma unroll
        for (int m = 0; m < 2; ++m) OT[te][m] = (f32x4){0.f, 0.f, 0.f, 0.f};
    lacc[0] = (f32x4){0.f, 0.f, 0.f, 0.f};
    lacc[1] = (f32x4){0.f, 0.f, 0.f, 0.f};

    const f32x4 Zc = (f32x4){0.f, 0.f, 0.f, 0.f};   // loop-invariant zero C
    bf16x8 ONES;
    #pragma unroll
    for (int i = 0; i < 8; ++i) ONES[i] = (short)0x3F80;   // bf16 1.0

    auto stage = [&](int kt, int buf) {
        #pragma unroll
        for (int i = 0; i < 2; ++i) {
            int rb = 16 * w + 8 * i;
            __builtin_amdgcn_global_load_lds(
                (const GLOBAL_AS void*)&K[(size_t)(kbase + kt + rb + srow) * HDIM
                                          + schunk * 8],
                (LDS_AS void*)&Klds[buf][rb * 64], 16, 0, 0);
            __builtin_amdgcn_global_load_lds(
                (const GLOBAL_AS void*)&Vt[(size_t)(rb + srow) * NPTS
                                           + kbase + kt + schunk * 8],
                (LDS_AS void*)&Vlds[buf][rb * 64], 16, 0, 0);
        }
    };

    stage(0, 0);
    __syncthreads();
    int buf = 0;

    for (int kt = 0; kt < NPTS / 2; kt += 64) {
        if (kt + 64 < NPTS / 2) stage(kt + 64, buf ^ 1);

        // K A-frags from LDS
        bf16x8 kf[4][2];
        #pragma unroll
        for (int kn = 0; kn < 4; ++kn) {
            kf[kn][0] = *(const bf16x8*)&Klds[buf][1024 * kn + koff0];
            kf[kn][1] = *(const bf16x8*)&Klds[buf][1024 * kn + koff1];
        }

        // S^T = K Q^T (zero-C hoisted: no per-iter accumulator init)
        f32x4 st[4][2];
        #pragma unroll
        for (int kn = 0; kn < 4; ++kn)
            #pragma unroll
            for (int m = 0; m < 2; ++m)
                st[kn][m] = __builtin_amdgcn_mfma_f32_16x16x32_bf16(
                    kf[kn][1], qf[m][1],
                    __builtin_amdgcn_mfma_f32_16x16x32_bf16(
                        kf[kn][0], qf[m][0], Zc, 0, 0, 0),
                    0, 0, 0);

        // V A-frags from LDS
        bf16x8 vf[4][2];
        #pragma unroll
        for (int te = 0; te < 4; ++te) {
            vf[te][0] = *(const bf16x8*)&Vlds[buf][1024 * te + koff0];
            vf[te][1] = *(const bf16x8*)&Vlds[buf][1024 * te + koff1];
        }

        // max-free softmax in registers: pt = bf16 exp2(S^T)
        bf16x8 pt[2][2];
        #pragma unroll
        for (int kb = 0; kb < 2; ++kb)
            #pragma unroll
            for (int m = 0; m < 2; ++m) {
                float a0 = EXP2F(st[2 * kb + 0][m][0]);
                float a1 = EXP2F(st[2 * kb + 0][m][1]);
                float a2 = EXP2F(st[2 * kb + 0][m][2]);
                float a3 = EXP2F(st[2 * kb + 0][m][3]);
                float b0 = EXP2F(st[2 * kb + 1][m][0]);
                float b1 = EXP2F(st[2 * kb + 1][m][1]);
                float b2 = EXP2F(st[2 * kb + 1][m][2]);
                float b3 = EXP2F(st[2 * kb + 1][m][3]);
                union { uint4 u; bf16x8 v; } uu;
                uu.u.x = pk2bf(a0, a1);
                uu.u.y = pk2bf(a2, a3);
                uu.u.z = pk2bf(b0, b1);
                uu.u.w = pk2bf(b2, b3);
                pt[kb][m] = uu.v;
            }

        // l-sums via ones-MFMA: lacc[m][r] = sum_k P^T[k][qrow] (rows equal)
        #pragma unroll
        for (int m = 0; m < 2; ++m) {
            lacc[m] = __builtin_amdgcn_mfma_f32_16x16x32_bf16(
                ONES, pt[0][m], lacc[m], 0, 0, 0);
            lacc[m] = __builtin_amdgcn_mfma_f32_16x16x32_bf16(
                ONES, pt[1][m], lacc[m], 0, 0, 0);
        }

        // O^T += V^T P^T  (pure register path)
        #pragma unroll
        for (int te = 0; te < 4; ++te)
            #pragma unroll
            for (int m = 0; m < 2; ++m) {
                OT[te][m] = __builtin_amdgcn_mfma_f32_16x16x32_bf16(
                    vf[te][0], pt[0][m], OT[te][m], 0, 0, 0);
                OT[te][m] = __builtin_amdgcn_mfma_f32_16x16x32_bf16(
                    vf[te][1], pt[1][m], OT[te][m], 0, 0, 0);
            }

        __syncthreads();   // Klds/Vlds[buf] reads done; next stage visible
        buf ^= 1;
    }

    // epilogue: lacc row 0 already holds the full key-sum for qrow=l15
    #pragma unroll
    for (int m = 0; m < 2; ++m) {
        int n = q0 + 32 * w + 16 * m + l15;
        if (quad == 0) lp[n] = lacc[m][0];
        #pragma unroll
        for (int te = 0; te < 4; ++te) {
            uint2 pk;
            pk.x = pk2bf(OT[te][m][0], OT[te][m][1]);
            pk.y = pk2bf(OT[te][m][2], OT[te][m][3]);
            *(uint2*)&op[(size_t)n * DIM + h * HDIM + 16 * te + quad * 4] = pk;
        }
    }
}

// ---------------------------------------------------------------------------
// Output projection with FUSED k-split merge + normalization:
// A-frag = bf16((op0 + op1) * 1/(l0 + l1)) computed inline; reduce_kernel
// deleted. out = merged @ Wo + bo + x.
// ---------------------------------------------------------------------------
__global__ __launch_bounds__(256) void out_mfma_kernel(
    const unsigned short* __restrict__ op0,   // [N][512] bf16 partial 0
    const unsigned short* __restrict__ op1,   // [N][512] bf16 partial 1
    const float* __restrict__ l0, const float* __restrict__ l1,  // [H][N]
    const unsigned short* __restrict__ wot,   // [512][512] bf16 [e_out][k]
    const float* __restrict__ bo, const float* __restrict__ x,
    float* __restrict__ outp)
{
    const int t = threadIdx.x, w = t >> 6, lane = t & 63;
    const int l15 = lane & 15, quad = lane >> 4;
    const int r0 = blockIdx.x * 128 + w * 32;
    const int c0 = blockIdx.y * 64;

    f32x4 O[2][4];
    #pragma unroll
    for (int mt = 0; mt < 2; ++mt)
        #pragma unroll
        for (int tn = 0; tn < 4; ++tn) O[mt][tn] = (f32x4){0.f, 0.f, 0.f, 0.f};

    for (int k0 = 0; k0 < DIM; k0 += 64) {
        const int hh = k0 >> 6;   // head for this k-chunk (HDIM=64)
        bf16x8 af[2][2], bf[4][2];
        #pragma unroll
        for (int mt = 0; mt < 2; ++mt) {
            int n = r0 + 16 * mt + l15;
            float inv = 1.0f / (l0[hh * NPTS + n] + l1[hh * NPTS + n]);
            #pragma unroll
            for (int kc = 0; kc < 2; ++kc) {
                size_t off = (size_t)n * DIM + k0 + quad * 8 + 32 * kc;
                uint4 a = *(const uint4*)&op0[off];
                uint4 b = *(const uint4*)&op1[off];
                union { uint4 u; bf16x8 v; } r;
                r.u.x = pk2bf((bf2f_lo(a.x) + bf2f_lo(b.x)) * inv,
                              (bf2f_hi(a.x) + bf2f_hi(b.x)) * inv);
                r.u.y = pk2bf((bf2f_lo(a.y) + bf2f_lo(b.y)) * inv,
                              (bf2f_hi(a.y) + bf2f_hi(b.y)) * inv);
                r.u.z = pk2bf((bf2f_lo(a.z) + bf2f_lo(b.z)) * inv,
                              (bf2f_hi(a.z) + bf2f_hi(b.z)) * inv);
                r.u.w = pk2bf((bf2f_lo(a.w) + bf2f_lo(b.w)) * inv,
                              (bf2f_hi(a.w) + bf2f_hi(b.w)) * inv);
                af[mt][kc] = r.v;
            }
        }
        #pragma unroll
        for (int tn = 0; tn < 4; ++tn)
            #pragma unroll
            for (int kc = 0; kc < 2; ++kc)
                bf[tn][kc] = *(const bf16x8*)
                    &wot[(size_t)(c0 + l15 + 16 * tn) * DIM + k0 + quad * 8 + 32 * kc];
        #pragma unroll
        for (int mt = 0; mt < 2; ++mt)
            #pragma unroll
            for (int tn = 0; tn < 4; ++tn) {
                O[mt][tn] = __builtin_amdgcn_mfma_f32_16x16x32_bf16(
                    af[mt][0], bf[tn][0], O[mt][tn], 0, 0, 0);
                O[mt][tn] = __builtin_amdgcn_mfma_f32_16x16x32_bf16(
                    af[mt][1], bf[tn][1], O[mt][tn], 0, 0, 0);
            }
    }

    #pragma unroll
    for (int mt = 0; mt < 2; ++mt)
        #pragma unroll
        for (int tn = 0; tn < 4; ++tn) {
            int e = c0 + l15 + 16 * tn;
            float be = bo[e];
            #pragma unroll
            for (int r = 0; r < 4; ++r) {
                int n = r0 + 16 * mt + quad * 4 + r;
                outp[(size_t)n * DIM + e] = O[mt][tn][r] + be + x[(size_t)n * DIM + e];
            }
        }
}

extern "C" void kernel_launch(void* const* d_in, const int* in_sizes, int n_in,
                              void* d_out, int out_size, void* d_ws, size_t ws_size,
                              hipStream_t stream) {
    const float* x  = (const float*)d_in[0];
    const float* Wq = (const float*)d_in[1];
    const float* bq = (const float*)d_in[2];
    const float* Wk = (const float*)d_in[3];
    const float* bk = (const float*)d_in[4];
    const float* Wv = (const float*)d_in[5];
    const float* bv = (const float*)d_in[6];
    const float* Wo = (const float*)d_in[7];
    const float* bo = (const float*)d_in[8];
    float* out = (float*)d_out;

    const size_t per = (size_t)NHEAD * NPTS * HDIM;            // 4M elems
    unsigned short* xbf   = (unsigned short*)d_ws;             //  8 MB
    unsigned short* wtq   = xbf + (size_t)NPTS * DIM;          //  1.5 MB
    unsigned short* wot   = wtq + (size_t)24 * HDIM * DIM;     //  0.5 MB
    unsigned short* q_bf  = wot + (size_t)DIM * DIM;           //  8 MB
    unsigned short* k_bf  = q_bf + per;                        //  8 MB
    unsigned short* vt_bf = k_bf + per;                        //  8 MB
    unsigned short* op0   = vt_bf + per;                       //  8 MB
    unsigned short* op1   = op0 + (size_t)NPTS * DIM;          //  8 MB
    float*          lpart = (float*)(op1 + (size_t)NPTS * DIM); // 512 KB
    // total ws: ~50.5 MB

    prep_kernel<<<dim3(2304), 256, 0, stream>>>(
        x, Wq, Wk, Wv, Wo, xbf, wtq, wot);
    qkv_mfma_kernel<<<dim3(NPTS / 128, 24), 256, 0, stream>>>(
        xbf, wtq, bq, bk, bv, q_bf, k_bf, vt_bf);
    attn_kernel<<<dim3(NPTS / 128, NHEAD, 2), 256, 0, stream>>>(
        q_bf, k_bf, vt_bf, op0, lpart);
    out_mfma_kernel<<<dim3(NPTS / 128, DIM / 64), 256, 0, stream>>>(
        op0, op1, lpart, lpart + (size_t)NHEAD * NPTS, wot, bo, x, out);
}